// Round 14
// baseline (280.288 us; speedup 1.0000x reference)
//
#include <hip/hip_runtime.h>
#include <math.h>

#define BB 32
#define CC 128
#define HH 64
#define WW 64
#define KK 4
#define OO 256
#define RED 32
#define HWSZ (HH*WW)
#define XT_W 66            // 64 + 2 halo, both rows and cols
#define GPLANE (XT_W*XT_W) // 4356 pixels per (b,g,s) plane

typedef __attribute__((ext_vector_type(8))) short bf16x8;
typedef __attribute__((ext_vector_type(4))) float f32x4;
typedef __attribute__((ext_vector_type(16))) float f32x16;

static __device__ __forceinline__ unsigned short f2bf(float f) {
    unsigned int u = __float_as_uint(f);
    u += 0x7FFF + ((u >> 16) & 1);   // RNE
    return (unsigned short)(u >> 16);
}

// async 16B global -> LDS (DMA path). HW writes wave-uniform base + lane*16;
// we always pass lane-linear dests so the pointer matches that layout.
static __device__ __forceinline__ void async16(unsigned short* lds, const unsigned short* g) {
    __builtin_amdgcn_global_load_lds(
        (const __attribute__((address_space(1))) unsigned int*)g,
        (__attribute__((address_space(3))) unsigned int*)lds, 16, 0, 0);
}

// ---------- Kernel 1: transpose x -> xt[b][g][s][row][col][8ch] (bf16, zero halo)
// SEG-MAJOR global layout (conv stages linearly; conflict-free b128 reads). + pool.
__global__ __launch_bounds__(256) void transpose_pool(const float* __restrict__ x,
        unsigned short* __restrict__ xt, float* __restrict__ partial) {
    __shared__ float lt[CC][65];
    int h = blockIdx.x & 63;
    int b = blockIdx.x >> 6;
    const float* xb = x + ((size_t)b * CC * HH + h) * WW;
    for (int i = threadIdx.x; i < CC * 16; i += 256) {
        int c = i >> 4, f4 = i & 15;
        float4 v = *(const float4*)(xb + (size_t)c * HWSZ + f4 * 4);
        lt[c][f4 * 4 + 0] = v.x;
        lt[c][f4 * 4 + 1] = v.y;
        lt[c][f4 * 4 + 2] = v.z;
        lt[c][f4 * 4 + 3] = v.w;
    }
    __syncthreads();
    for (int i = threadIdx.x; i < 16 * 64; i += 256) {
        int cs = i >> 6, ww = i & 63;          // cs: 8-ch group; g = cs>>2, s = cs&3
        bf16x8 pk;
#pragma unroll
        for (int j = 0; j < 8; ++j) pk[j] = (short)f2bf(lt[cs * 8 + j][ww]);
        size_t plane = ((size_t)b * 4 + (cs >> 2)) * 4 + (cs & 3);
        *(bf16x8*)&xt[((plane * XT_W + (h + 1)) * XT_W + (ww + 1)) * 8] = pk;
    }
    if (threadIdx.x < 32) {
        int cs = threadIdx.x & 15;
        int col = (threadIdx.x < 16) ? 0 : 65;
        size_t plane = ((size_t)b * 4 + (cs >> 2)) * 4 + (cs & 3);
        *(f32x4*)&xt[((plane * XT_W + (h + 1)) * XT_W + col) * 8] =
            (f32x4){0.f, 0.f, 0.f, 0.f};
    }
    if (h == 0 || h == 63) {
        int hr = (h == 0) ? 0 : 65;
        for (int i = threadIdx.x; i < XT_W * 16; i += 256) {
            int px = i >> 4, cs = i & 15;
            size_t plane = ((size_t)b * 4 + (cs >> 2)) * 4 + (cs & 3);
            *(f32x4*)&xt[((plane * XT_W + hr) * XT_W + px) * 8] =
                (f32x4){0.f, 0.f, 0.f, 0.f};
        }
    }
    if (threadIdx.x < CC) {
        float s = 0.f;
#pragma unroll
        for (int j = 0; j < WW; ++j) s += lt[threadIdx.x][j];   // stride-65 rows: conflict-free
        partial[(size_t)blockIdx.x * CC + threadIdx.x] = s;
    }
}

// ---------- Kernel 2: h-reduce partials + MLP + softmax -> att[B][K] ----------
__global__ void att_kernel(const float* __restrict__ partial,
        const float* __restrict__ w1, const float* __restrict__ b1,
        const float* __restrict__ w2, const float* __restrict__ b2,
        float* __restrict__ att) {
    int b = blockIdx.x;
    int tid = threadIdx.x;
    __shared__ float ps[CC];
    __shared__ float hs[RED];
    __shared__ float ls[KK];
    if (tid < CC) {
        const float* pp = partial + (size_t)b * HH * CC + tid;
        float s = 0.f;
#pragma unroll
        for (int h = 0; h < HH; ++h) s += pp[(size_t)h * CC];
        ps[tid] = s * (1.0f / (float)HWSZ);
    }
    __syncthreads();
    int r = tid >> 3, j = tid & 7;
    const float* w1r = w1 + r * CC + j * 16;
    float p = 0.f;
#pragma unroll
    for (int c = 0; c < 16; ++c) p = fmaf(ps[j * 16 + c], w1r[c], p);
    p += __shfl_xor(p, 1, 64);
    p += __shfl_xor(p, 2, 64);
    p += __shfl_xor(p, 4, 64);
    if (j == 0) hs[r] = fmaxf(p + b1[r], 0.f);
    __syncthreads();
    if (tid < KK) {
        float acc = b2[tid];
        const float* w2k = w2 + tid * RED;
#pragma unroll
        for (int rr = 0; rr < RED; ++rr) acc = fmaf(hs[rr], w2k[rr], acc);
        ls[tid] = acc;
    }
    __syncthreads();
    if (tid == 0) {
        float m = fmaxf(fmaxf(ls[0], ls[1]), fmaxf(ls[2], ls[3]));
        float e0 = expf(ls[0] - m), e1 = expf(ls[1] - m);
        float e2 = expf(ls[2] - m), e3 = expf(ls[3] - m);
        float inv = 1.0f / (e0 + e1 + e2 + e3);
        att[b * KK + 0] = e0 * inv; att[b * KK + 1] = e1 * inv;
        att[b * KK + 2] = e2 * inv; att[b * KK + 3] = e3 * inv;
    }
}

// ---------- Kernel 3: mix weights -> bf16 wk[b][g][t][s][o][8ch]  (SEG-MAJOR) ----------
__global__ __launch_bounds__(256) void mix_kernel(const float* __restrict__ w,
        const float* __restrict__ att, unsigned short* __restrict__ wk) {
    int gid = blockIdx.x * 256 + threadIdx.x;
    int c = gid & 127;
    int o = (gid >> 7) & 255;
    int b = gid >> 15;
    float a[KK];
#pragma unroll
    for (int k = 0; k < KK; ++k) a[k] = att[b * KK + k];
    float mixed[9];
#pragma unroll
    for (int t = 0; t < 9; ++t) mixed[t] = 0.f;
#pragma unroll
    for (int k = 0; k < KK; ++k) {
        const float* p = w + (((size_t)k * OO + o) * CC + c) * 9;
#pragma unroll
        for (int t = 0; t < 9; ++t) mixed[t] = fmaf(a[k], p[t], mixed[t]);
    }
    int g = c >> 5, s = (c >> 3) & 3, j = c & 7;
    // wk[b][g][t][s][o][8]: per (b,g,t) block = 4*256*8 = 8192 shorts
    size_t base = ((size_t)b * 4 + g) * 9 * 8192 + ((size_t)s * 256 + o) * 8 + j;
#pragma unroll
    for (int t = 0; t < 9; ++t)
        wk[base + (size_t)t * 8192] = f2bf(mixed[t]);
}

// ---------- Kernel 4: MFMA implicit-GEMM conv ----------
// Ledger (conv us): R1 84; R2 93.5; R3 394; R4 global-A-old-layout 123; R5 93.4;
// R6 93; R8 86.5; R9 132; R10 81.3; R11 seg-major 78.4 BEST; R12 104.7; R13
// private-als no-barrier 82-85 (rendezvous NOT the residual).
// Corrected pipe model (4 waves/block, 8/CU): LDS 6912 b128/CU = 34.6us; MFMA
// 9216/CU = 31us — BALANCED pipes; only removing LDS work can move the floor.
// This round: A-operand streamed from L2 DIRECTLY to VGPRs (no als at all).
//  - A has zero intra-block reuse across taps (pure stream) -> LDS staging of A
//    buys nothing; only xs (9x reuse/g) earns LDS.
//  - R4's global-A failure was the OLD [o][c128] layout (64B-of-256B lines ->
//    FETCH 120MB). Seg-major wk: per-(t,m,kk) wave load = two dense 512B
//    segments, fully coalesced; per-XCD wk set 2.4MB < 4MB L2.
//  - Per wave-tap: 8 ds_read (B) + 4 global dwordx4 (A). LDS pipe 34.6 -> 23us;
//    MFMA (31us) becomes the binding pipe. A dbuf in regs af[2][2][2],
//    statically indexed after full unroll. Zero barriers in tap loop.
//  - LDS 25344 B; ~200 regs -> 2 blocks/CU.
#define XSP 396            // 6*66 pixels per s-plane in xs tile
__global__ __launch_bounds__(256, 2) void conv_mfma(const unsigned short* __restrict__ xt,
        const unsigned short* __restrict__ wk, float* __restrict__ out) {
    __shared__ unsigned short xs[4 * XSP * 8];          // [s][pix][8ch] = 25344 B

    // XCD-contiguous swizzle: XCD x gets logical blocks x*128 .. x*128+127 (= 4 samples)
    int bid = blockIdx.x;
    int blk = (bid & 7) * 128 + (bid >> 3);
    int b  = blk >> 5;
    int rg = (blk >> 1) & 15;   // ot fastest: both o-halves of a row-group adjacent
    int ot = blk & 1;
    int r0 = rg * 4;
    int o0 = ot * 128;

    int tid = threadIdx.x;
    int lane = tid & 63;
    int wid = tid >> 6;
    int wm = wid & 1;           // o half within block's 128
    int wn = wid >> 1;          // output row pair (2 rows each)
    int l31 = lane & 31;
    int lh = lane >> 5;         // k-half selector

    f32x16 acc[2][4];
#pragma unroll
    for (int i = 0; i < 2; ++i)
#pragma unroll
        for (int j = 0; j < 4; ++j)
#pragma unroll
            for (int r = 0; r < 16; ++r) acc[i][j][r] = 0.f;

    // xt[b][g][s][row][col][8]: per (b) = 4*4*4356*8 shorts
    const unsigned short* xt_b = xt + (size_t)b * 4 * 4 * GPLANE * 8;
    // wk[b][g][t][s][o][8]: per (b) = 4*9*8192 shorts
    const unsigned short* wk_b = wk + (size_t)b * 4 * 9 * 8192;
    int obase = o0 + wm * 64;   // this wave's 64-o slice

    for (int g = 0; g < 4; ++g) {
        const unsigned short* xsg  = xt_b + (size_t)g * 4 * GPLANE * 8;
        const unsigned short* wsrc = wk_b + (size_t)g * 9 * 8192;
        // per-lane A base: seg plane lh, o-row obase+l31 (fragment offsets are
        // compile-time: tap*8192 + kk*4096 + m*256 shorts)
        const unsigned short* wk_w = wsrc + (size_t)lh * 2048 + ((size_t)obase + l31) * 8;

        __syncthreads();                 // all waves done reading prior g's xs
        // stage xs: [s][pix 0..395] <- xt plane s rows r0..r0+5 (linear chunk map)
        for (int i = tid; i < 4 * XSP; i += 256) {
            int s = i / XSP, pix = i - s * XSP;
            async16(xs + (size_t)i * 8,
                    xsg + ((size_t)s * GPLANE + r0 * XT_W + pix) * 8);
        }
        __syncthreads();                 // drains xs DMAs (vmcnt0 before barrier)

        // A register double-buffer, statically indexed after full unroll
        bf16x8 af[2][2][2];              // [parity][m][kk]
#pragma unroll
        for (int m = 0; m < 2; ++m)
#pragma unroll
            for (int kk = 0; kk < 2; ++kk)
                af[0][m][kk] = *(const bf16x8*)(wk_w + kk * 4096 + m * 256);

#pragma unroll
        for (int t = 0; t < 9; ++t) {
            // prefetch A(t+1) into the other parity (compiler emits counted vmcnt)
            if (t < 8) {
#pragma unroll
                for (int m = 0; m < 2; ++m)
#pragma unroll
                    for (int kk = 0; kk < 2; ++kk)
                        af[(t + 1) & 1][m][kk] = *(const bf16x8*)
                            (wk_w + (size_t)(t + 1) * 8192 + kk * 4096 + m * 256);
            }
            int kh = t / 3, kw = t - kh * 3;
            // B: [nf][kk] from shared xs, 32x16B contiguous per half-wave
            bf16x8 bfv[4][2];
#pragma unroll
            for (int nf = 0; nf < 4; ++nf) {
                int prow = wn * 2 + (nf >> 1) + kh;
                int pcol = (nf & 1) * 32 + l31 + kw;
                int pix = prow * XT_W + pcol;
#pragma unroll
                for (int kk = 0; kk < 2; ++kk) {
                    int s = kk * 2 + lh;
                    bfv[nf][kk] = *(const bf16x8*)&xs[((size_t)s * XSP + pix) * 8];
                }
            }
#pragma unroll
            for (int kk = 0; kk < 2; ++kk)
#pragma unroll
                for (int m = 0; m < 2; ++m)
#pragma unroll
                    for (int nf = 0; nf < 4; ++nf)
                        acc[m][nf] = __builtin_amdgcn_mfma_f32_32x32x16_bf16(
                            af[t & 1][m][kk], bfv[nf][kk], acc[m][nf], 0, 0, 0);
            // no barrier: xs read-only within g; A is register-private.
        }
    }

    float* outb = out + ((size_t)b * OO + o0) * HWSZ;
#pragma unroll
    for (int m = 0; m < 2; ++m)
#pragma unroll
        for (int nf = 0; nf < 4; ++nf) {
            int row = r0 + wn * 2 + (nf >> 1);
            int col = (nf & 1) * 32 + l31;
#pragma unroll
            for (int r = 0; r < 16; ++r) {
                int o = wm * 64 + m * 32 + (r & 3) + 8 * (r >> 2) + 4 * lh;
                __builtin_nontemporal_store(acc[m][nf][r],
                    &outb[(size_t)o * HWSZ + row * WW + col]);
            }
        }
}

extern "C" void kernel_launch(void* const* d_in, const int* in_sizes, int n_in,
                              void* d_out, int out_size, void* d_ws, size_t ws_size,
                              hipStream_t stream) {
    const float* x       = (const float*)d_in[0];
    const float* weights = (const float*)d_in[1];
    const float* w1      = (const float*)d_in[2];
    const float* b1      = (const float*)d_in[3];
    const float* w2      = (const float*)d_in[4];
    const float* b2      = (const float*)d_in[5];
    float* out = (float*)d_out;

    char* ws = (char*)d_ws;
    float* partial      = (float*)ws;                               // 2048*128*4 = 1 MB
    float* att          = (float*)(ws + 1048576);                   // 512 B
    unsigned short* wk  = (unsigned short*)(ws + 1048576 + 4096);   // 18.87 MB
    unsigned short* xtp = (unsigned short*)(ws + 1048576 + 4096 + 18874368); // 35.68 MB

    transpose_pool<<<BB * HH, 256, 0, stream>>>(x, xtp, partial);
    att_kernel<<<BB, 256, 0, stream>>>(partial, w1, b1, w2, b2, att);
    mix_kernel<<<BB * OO * CC / 256, 256, 0, stream>>>(weights, att, wk);
    conv_mfma<<<BB * 2 * 16, 256, 0, stream>>>(xtp, wk, out);
}

// Round 15
// 266.221 us; speedup vs baseline: 1.0528x; 1.0528x over previous
//
#include <hip/hip_runtime.h>
#include <math.h>

#define BB 32
#define CC 128
#define HH 64
#define WW 64
#define KK 4
#define OO 256
#define RED 32
#define HWSZ (HH*WW)
#define XT_W 66            // 64 + 2 halo, both rows and cols
#define GPLANE (XT_W*XT_W) // 4356 pixels per (b,g,s) plane

typedef __attribute__((ext_vector_type(8))) short bf16x8;
typedef __attribute__((ext_vector_type(4))) float f32x4;
typedef __attribute__((ext_vector_type(16))) float f32x16;

static __device__ __forceinline__ unsigned short f2bf(float f) {
    unsigned int u = __float_as_uint(f);
    u += 0x7FFF + ((u >> 16) & 1);   // RNE
    return (unsigned short)(u >> 16);
}

// async 16B global -> LDS (DMA path, no VGPR round-trip). LDS dest is
// wave-uniform base + lane*16 (our i = k*256+tid indexing satisfies this).
static __device__ __forceinline__ void async16(unsigned short* lds, const unsigned short* g) {
    __builtin_amdgcn_global_load_lds(
        (const __attribute__((address_space(1))) unsigned int*)g,
        (__attribute__((address_space(3))) unsigned int*)lds, 16, 0, 0);
}

// ---------- Kernel 1: transpose x -> xt[b][g][s][row][col][8ch] (bf16, zero halo)
// SEG-MAJOR global layout: conv's LDS tile [s][pix] stages linearly from this,
// making all conv ds_read_b128 fully contiguous (conflict-free). + pool partials.
__global__ __launch_bounds__(256) void transpose_pool(const float* __restrict__ x,
        unsigned short* __restrict__ xt, float* __restrict__ partial) {
    __shared__ float lt[CC][65];
    int h = blockIdx.x & 63;
    int b = blockIdx.x >> 6;
    const float* xb = x + ((size_t)b * CC * HH + h) * WW;
    for (int i = threadIdx.x; i < CC * 16; i += 256) {
        int c = i >> 4, f4 = i & 15;
        float4 v = *(const float4*)(xb + (size_t)c * HWSZ + f4 * 4);
        lt[c][f4 * 4 + 0] = v.x;
        lt[c][f4 * 4 + 1] = v.y;
        lt[c][f4 * 4 + 2] = v.z;
        lt[c][f4 * 4 + 3] = v.w;
    }
    __syncthreads();
    // interior: i = cs*64 + ww -> 64 consecutive threads write 1KB contiguous
    for (int i = threadIdx.x; i < 16 * 64; i += 256) {
        int cs = i >> 6, ww = i & 63;          // cs: 8-ch group; g = cs>>2, s = cs&3
        bf16x8 pk;
#pragma unroll
        for (int j = 0; j < 8; ++j) pk[j] = (short)f2bf(lt[cs * 8 + j][ww]);
        size_t plane = ((size_t)b * 4 + (cs >> 2)) * 4 + (cs & 3);
        *(bf16x8*)&xt[((plane * XT_W + (h + 1)) * XT_W + (ww + 1)) * 8] = pk;
    }
    // col halo (cols 0 and 65) for this row
    if (threadIdx.x < 32) {
        int cs = threadIdx.x & 15;
        int col = (threadIdx.x < 16) ? 0 : 65;
        size_t plane = ((size_t)b * 4 + (cs >> 2)) * 4 + (cs & 3);
        *(f32x4*)&xt[((plane * XT_W + (h + 1)) * XT_W + col) * 8] =
            (f32x4){0.f, 0.f, 0.f, 0.f};
    }
    // row halo (rows 0 and 65)
    if (h == 0 || h == 63) {
        int hr = (h == 0) ? 0 : 65;
        for (int i = threadIdx.x; i < XT_W * 16; i += 256) {
            int px = i >> 4, cs = i & 15;
            size_t plane = ((size_t)b * 4 + (cs >> 2)) * 4 + (cs & 3);
            *(f32x4*)&xt[((plane * XT_W + hr) * XT_W + px) * 8] =
                (f32x4){0.f, 0.f, 0.f, 0.f};
        }
    }
    if (threadIdx.x < CC) {
        float s = 0.f;
#pragma unroll
        for (int j = 0; j < WW; ++j) s += lt[threadIdx.x][j];   // stride-65 rows: conflict-free
        partial[(size_t)blockIdx.x * CC + threadIdx.x] = s;
    }
}

// ---------- Kernel 2: h-reduce partials + MLP + softmax -> att[B][K] ----------
__global__ void att_kernel(const float* __restrict__ partial,
        const float* __restrict__ w1, const float* __restrict__ b1,
        const float* __restrict__ w2, const float* __restrict__ b2,
        float* __restrict__ att) {
    int b = blockIdx.x;
    int tid = threadIdx.x;
    __shared__ float ps[CC];
    __shared__ float hs[RED];
    __shared__ float ls[KK];
    if (tid < CC) {
        const float* pp = partial + (size_t)b * HH * CC + tid;
        float s = 0.f;
#pragma unroll
        for (int h = 0; h < HH; ++h) s += pp[(size_t)h * CC];
        ps[tid] = s * (1.0f / (float)HWSZ);
    }
    __syncthreads();
    int r = tid >> 3, j = tid & 7;
    const float* w1r = w1 + r * CC + j * 16;
    float p = 0.f;
#pragma unroll
    for (int c = 0; c < 16; ++c) p = fmaf(ps[j * 16 + c], w1r[c], p);
    p += __shfl_xor(p, 1, 64);
    p += __shfl_xor(p, 2, 64);
    p += __shfl_xor(p, 4, 64);
    if (j == 0) hs[r] = fmaxf(p + b1[r], 0.f);
    __syncthreads();
    if (tid < KK) {
        float acc = b2[tid];
        const float* w2k = w2 + tid * RED;
#pragma unroll
        for (int rr = 0; rr < RED; ++rr) acc = fmaf(hs[rr], w2k[rr], acc);
        ls[tid] = acc;
    }
    __syncthreads();
    if (tid == 0) {
        float m = fmaxf(fmaxf(ls[0], ls[1]), fmaxf(ls[2], ls[3]));
        float e0 = expf(ls[0] - m), e1 = expf(ls[1] - m);
        float e2 = expf(ls[2] - m), e3 = expf(ls[3] - m);
        float inv = 1.0f / (e0 + e1 + e2 + e3);
        att[b * KK + 0] = e0 * inv; att[b * KK + 1] = e1 * inv;
        att[b * KK + 2] = e2 * inv; att[b * KK + 3] = e3 * inv;
    }
}

// ---------- Kernel 3: mix weights -> bf16 wk[b][g][t][s][o][8ch]  (SEG-MAJOR) ----------
__global__ __launch_bounds__(256) void mix_kernel(const float* __restrict__ w,
        const float* __restrict__ att, unsigned short* __restrict__ wk) {
    int gid = blockIdx.x * 256 + threadIdx.x;
    int c = gid & 127;
    int o = (gid >> 7) & 255;
    int b = gid >> 15;
    float a[KK];
#pragma unroll
    for (int k = 0; k < KK; ++k) a[k] = att[b * KK + k];
    float mixed[9];
#pragma unroll
    for (int t = 0; t < 9; ++t) mixed[t] = 0.f;
#pragma unroll
    for (int k = 0; k < KK; ++k) {
        const float* p = w + (((size_t)k * OO + o) * CC + c) * 9;
#pragma unroll
        for (int t = 0; t < 9; ++t) mixed[t] = fmaf(a[k], p[t], mixed[t]);
    }
    int g = c >> 5, s = (c >> 3) & 3, j = c & 7;
    // wk[b][g][t][s][o][8]: per (b,g,t) block = 4*256*8 = 8192 shorts
    size_t base = ((size_t)b * 4 + g) * 9 * 8192 + ((size_t)s * 256 + o) * 8 + j;
#pragma unroll
    for (int t = 0; t < 9; ++t)
        wk[base + (size_t)t * 8192] = f2bf(mixed[t]);
}

// ---------- Kernel 4: MFMA implicit-GEMM conv ----------
// FINAL (revert to proven best = R11). Full ledger (conv us):
//   R1 relayout+DMA 84 | R2 cvmcnt+2bar 93.5 | R3 spill 394 | R4 global-A 123
//   R5 small-tile 93.4 | R6 3-tap grp 93 | R8 32x32 shape 86.5 | R9 1-wave 132
//   R10 tbuf+vmcnt(2) 81.3 | R11 seg-major conflict-free 78.4 BEST
//   R12 dist2+setprio 104.7 | R13 wave-private no-barrier 82-85 | R14 L2-A 95
// Post-R11 rounds eliminated: DMA-latency depth (R12), barrier rendezvous (R13),
// LDS-pipe load (R14). Residual ~35us above the 31us MFMA floor is the
// serialization intrinsic to this balanced structure; every plain-HIP
// scheduling lever tested against it lost. Winning levers were all
// layout/shape: g-major + XCD swizzle (FETCH 198->27MB), 16B DMA staging,
// 32x32x16 shape, seg-major conflict-free LDS (7.08M->0), tbuf+counted vmcnt.
#define XSP 396            // 6*66 pixels per s-plane in xs tile
__global__ __launch_bounds__(256, 2) void conv_mfma(const unsigned short* __restrict__ xt,
        const unsigned short* __restrict__ wk, float* __restrict__ out) {
    __shared__ unsigned short xs[4 * XSP * 8];          // [s][pix][8ch] = 25344 B
    __shared__ unsigned short als[3][4 * 128 * 8];      // [s][o_local][8ch] = 8KB x3

    // XCD-contiguous swizzle: XCD x gets logical blocks x*128 .. x*128+127 (= 4 samples)
    int bid = blockIdx.x;
    int blk = (bid & 7) * 128 + (bid >> 3);
    int b  = blk >> 5;
    int rg = (blk >> 1) & 15;   // ot fastest: both o-halves of a row-group adjacent
    int ot = blk & 1;
    int r0 = rg * 4;
    int o0 = ot * 128;

    int tid = threadIdx.x;
    int lane = tid & 63;
    int wid = tid >> 6;
    int wm = wid & 1;           // o half within block's 128
    int wn = wid >> 1;          // output row pair (2 rows each)
    int l31 = lane & 31;
    int lh = lane >> 5;         // k-half selector

    f32x16 acc[2][4];
#pragma unroll
    for (int i = 0; i < 2; ++i)
#pragma unroll
        for (int j = 0; j < 4; ++j)
#pragma unroll
            for (int r = 0; r < 16; ++r) acc[i][j][r] = 0.f;

    // xt[b][g][s][row][col][8]: per (b) = 4*4*4356*8 shorts
    const unsigned short* xt_b = xt + (size_t)b * 4 * 4 * GPLANE * 8;
    // wk[b][g][t][s][o][8]: per (b) = 4*9*8192 shorts
    const unsigned short* wk_b = wk + (size_t)b * 4 * 9 * 8192;

    for (int g = 0; g < 4; ++g) {
        const unsigned short* xsg  = xt_b + (size_t)g * 4 * GPLANE * 8;
        const unsigned short* wsrc = wk_b + (size_t)g * 9 * 8192;
        __syncthreads();                 // full drain: prior g's reads done before overwrite
        // stage xs: [s][pix 0..395] <- xt plane s rows r0..r0+5 (linear chunk map)
        for (int i = tid; i < 4 * XSP; i += 256) {
            int s = i / XSP, pix = i - s * XSP;
            async16(xs + (size_t)i * 8,
                    xsg + ((size_t)s * GPLANE + r0 * XT_W + pix) * 8);
        }
        // stage als[0] (tap 0): [s][o_local] <- wk tap 0, o0 half (linear)
        {
            int ch = tid;
#pragma unroll
            for (int rep = 0; rep < 2; ++rep, ch += 256) {
                async16(als[0] + (size_t)ch * 8,
                        wsrc + ((size_t)(ch >> 7) * 256 + o0 + (ch & 127)) * 8);
            }
        }
        __syncthreads();   // full drain: xs + als[0] resident

#pragma unroll
        for (int t = 0; t < 9; ++t) {
            // issue next tap's als into buf (t+1)%3 (2 loads/thread, uniform count).
            // Laggards read buf (t-1)%3 — disjoint — so ONE barrier/tap suffices.
            if (t < 8) {
                int nb = (t + 1) % 3;
                const unsigned short* tsrc = wsrc + (size_t)(t + 1) * 8192;
                int ch = tid;
#pragma unroll
                for (int rep = 0; rep < 2; ++rep, ch += 256) {
                    async16(als[nb] + (size_t)ch * 8,
                            tsrc + ((size_t)(ch >> 7) * 256 + o0 + (ch & 127)) * 8);
                }
                // own tap-t DMAs (issued last tap) done; t+1's 2 stay in flight
                asm volatile("s_waitcnt vmcnt(2)" ::: "memory");
            } else {
                asm volatile("s_waitcnt vmcnt(0)" ::: "memory");
            }
            __builtin_amdgcn_s_barrier();      // all waves' tap-t data in LDS
            asm volatile("" ::: "memory");     // no LDS reads hoist above barrier

            int kh = t / 3, kw = t - kh * 3;
            const unsigned short* alsb = als[t % 3];
            // A: [m][kk], contiguous 32x16B per half-wave (conflict-free)
            bf16x8 af[2][2], bfv[4][2];
#pragma unroll
            for (int m = 0; m < 2; ++m) {
                int orow = wm * 64 + m * 32 + l31;
#pragma unroll
                for (int kk = 0; kk < 2; ++kk) {
                    int s = kk * 2 + lh;
                    af[m][kk] = *(const bf16x8*)&alsb[((size_t)s * 128 + orow) * 8];
                }
            }
            // B: [nf][kk], contiguous 32x16B per half-wave (conflict-free)
#pragma unroll
            for (int nf = 0; nf < 4; ++nf) {
                int prow = wn * 2 + (nf >> 1) + kh;
                int pcol = (nf & 1) * 32 + l31 + kw;
                int pix = prow * XT_W + pcol;
#pragma unroll
                for (int kk = 0; kk < 2; ++kk) {
                    int s = kk * 2 + lh;
                    bfv[nf][kk] = *(const bf16x8*)&xs[((size_t)s * XSP + pix) * 8];
                }
            }
#pragma unroll
            for (int kk = 0; kk < 2; ++kk)
#pragma unroll
                for (int m = 0; m < 2; ++m)
#pragma unroll
                    for (int nf = 0; nf < 4; ++nf)
                        acc[m][nf] = __builtin_amdgcn_mfma_f32_32x32x16_bf16(
                            af[m][kk], bfv[nf][kk], acc[m][nf], 0, 0, 0);
            // no trailing barrier (triple-buffer makes early issue safe)
        }
    }

    float* outb = out + ((size_t)b * OO + o0) * HWSZ;
#pragma unroll
    for (int m = 0; m < 2; ++m)
#pragma unroll
        for (int nf = 0; nf < 4; ++nf) {
            int row = r0 + wn * 2 + (nf >> 1);
            int col = (nf & 1) * 32 + l31;
#pragma unroll
            for (int r = 0; r < 16; ++r) {
                int o = wm * 64 + m * 32 + (r & 3) + 8 * (r >> 2) + 4 * lh;
                __builtin_nontemporal_store(acc[m][nf][r],
                    &outb[(size_t)o * HWSZ + row * WW + col]);
            }
        }
}

extern "C" void kernel_launch(void* const* d_in, const int* in_sizes, int n_in,
                              void* d_out, int out_size, void* d_ws, size_t ws_size,
                              hipStream_t stream) {
    const float* x       = (const float*)d_in[0];
    const float* weights = (const float*)d_in[1];
    const float* w1      = (const float*)d_in[2];
    const float* b1      = (const float*)d_in[3];
    const float* w2      = (const float*)d_in[4];
    const float* b2      = (const float*)d_in[5];
    float* out = (float*)d_out;

    char* ws = (char*)d_ws;
    float* partial      = (float*)ws;                               // 2048*128*4 = 1 MB
    float* att          = (float*)(ws + 1048576);                   // 512 B
    unsigned short* wk  = (unsigned short*)(ws + 1048576 + 4096);   // 18.87 MB
    unsigned short* xtp = (unsigned short*)(ws + 1048576 + 4096 + 18874368); // 35.68 MB

    transpose_pool<<<BB * HH, 256, 0, stream>>>(x, xtp, partial);
    att_kernel<<<BB, 256, 0, stream>>>(partial, w1, b1, w2, b2, att);
    mix_kernel<<<BB * OO * CC / 256, 256, 0, stream>>>(weights, att, wk);
    conv_mfma<<<BB * 2 * 16, 256, 0, stream>>>(xtp, wk, out);
}